// Round 5
// baseline (206.737 us; speedup 1.0000x reference)
//
#include <hip/hip_runtime.h>
#include <hip/hip_cooperative_groups.h>
#include <math.h>

namespace cg = cooperative_groups;

// Problem constants (B=16, T=2048, D=1024, K=8)
#define BT    32768   // B*T rows
#define DD    1024    // D
#define DV    256     // float4 per row (D/4)
#define KC    8       // clusters
#define NBLK  512     // grid: 2 blocks/CU, all co-resident (cooperative)
#define RPB   64      // rows per block = BT/NBLK

// clang native vector type (required by __builtin_nontemporal_store).
typedef float fv4 __attribute__((ext_vector_type(4)));

// ---------------------------------------------------------------------------
// One cooperative kernel, three phases separated by grid.sync():
//   P1: per-block column partial sums  -> part[NBLK][DD]     (non-atomic)
//   P2a: 256 blocks fold part -> colsum[DD] (2 loads/thread + LDS tree)
//   P2b: every block redundantly computes r[0..7] from colsum (4KB, parallel)
//   P3: elementwise famil/GELU pass over the block's own 64 rows, NT store.
// Fusion removes the single-block k2 bottleneck and two kernel boundaries,
// and makes the whole op ONE dispatch (visible in rocprof top-5).
// ---------------------------------------------------------------------------
__global__ __launch_bounds__(256, 2) void fused(
        const float* __restrict__ x,
        const float* __restrict__ mus,
        const float* __restrict__ wmix,
        const float* __restrict__ log_tau,
        const float* __restrict__ log_blend,
        float* __restrict__ out,
        float* __restrict__ part,
        float* __restrict__ colsum) {
    const int tid = threadIdx.x;
    const int bid = blockIdx.x;
    cg::grid_group grid = cg::this_grid();

    const fv4* xv = (const fv4*)x;
    const long row0 = (long)bid * RPB;

    // ---- Phase 1: column partial sums, 8-deep batched loads --------------
    {
        fv4 acc = (fv4)(0.f);
        for (int r = 0; r < RPB; r += 8) {
            fv4 v[8];
#pragma unroll
            for (int i = 0; i < 8; ++i)
                v[i] = xv[(row0 + r + i) * DV + tid];
#pragma unroll
            for (int i = 0; i < 8; ++i) acc += v[i];
        }
        ((fv4*)part)[(long)bid * DV + tid] = acc;
    }
    grid.sync();

    // ---- Phase 2a: fold partials (block b < 256 owns fv4-column b) -------
    __shared__ fv4 red[256];
    if (bid < DV) {
        fv4 a = ((const fv4*)part)[(long)tid * DV + bid] +
                ((const fv4*)part)[(long)(tid + 256) * DV + bid];
        red[tid] = a;
        __syncthreads();
#pragma unroll
        for (int s = 128; s > 0; s >>= 1) {
            if (tid < s) red[tid] += red[tid + s];
            __syncthreads();
        }
        if (tid == 0) ((fv4*)colsum)[bid] = red[0];
    }
    grid.sync();

    // ---- Phase 2b: every block computes r[0..7] redundantly --------------
    float rk[KC];
    {
        const float inv_bt = 1.0f / (float)BT;
        fv4 s = ((const fv4*)colsum)[tid];
        float m[4] = { s.x * inv_bt, s.y * inv_bt, s.z * inv_bt, s.w * inv_bt };
        float prt[KC];
#pragma unroll
        for (int k = 0; k < KC; ++k) {
            fv4 mu = ((const fv4*)mus)[k * DV + tid];
            float d0 = m[0] - mu.x, d1 = m[1] - mu.y;
            float d2 = m[2] - mu.z, d3 = m[3] - mu.w;
            prt[k] = d0 * d0 + d1 * d1 + d2 * d2 + d3 * d3;
        }
        __shared__ float l2[KC][4];
        const int lane = tid & 63, wv = tid >> 6;
#pragma unroll
        for (int k = 0; k < KC; ++k) {
            float v = prt[k];
#pragma unroll
            for (int off = 32; off > 0; off >>= 1) v += __shfl_down(v, off, 64);
            if (lane == 0) l2[k][wv] = v;
        }
        __syncthreads();
        // every thread computes the K=8 softmax (cheap, avoids another sync)
        float logits[KC], mx = -1e30f;
#pragma unroll
        for (int k = 0; k < KC; ++k) {
            float tot = l2[k][0] + l2[k][1] + l2[k][2] + l2[k][3];
            float dist = sqrtf(tot * (1.0f / (float)DD));
            logits[k] = logf(wmix[k]) - dist;
            mx = fmaxf(mx, logits[k]);
        }
        float se = 0.f, e[KC];
#pragma unroll
        for (int k = 0; k < KC; ++k) { e[k] = expf(logits[k] - mx); se += e[k]; }
        float is = 1.f / se;
#pragma unroll
        for (int k = 0; k < KC; ++k) rk[k] = e[k] * is;
    }

    // ---- Phase 3: elementwise famil/GELU over this block's 64 rows -------
    {
        const float LOG2E = 1.44269504f;
        fv4 lt = ((const fv4*)log_tau)[tid];
        fv4 lb = ((const fv4*)log_blend)[tid];
        float tl[4], al[4];
        tl[0] = __builtin_amdgcn_exp2f(lt.x * LOG2E) * LOG2E;
        tl[1] = __builtin_amdgcn_exp2f(lt.y * LOG2E) * LOG2E;
        tl[2] = __builtin_amdgcn_exp2f(lt.z * LOG2E) * LOG2E;
        tl[3] = __builtin_amdgcn_exp2f(lt.w * LOG2E) * LOG2E;
        al[0] = 1.f / (1.f + __builtin_amdgcn_exp2f(-lb.x * LOG2E));
        al[1] = 1.f / (1.f + __builtin_amdgcn_exp2f(-lb.y * LOG2E));
        al[2] = 1.f / (1.f + __builtin_amdgcn_exp2f(-lb.z * LOG2E));
        al[3] = 1.f / (1.f + __builtin_amdgcn_exp2f(-lb.w * LOG2E));

        float mu[KC][4];
#pragma unroll
        for (int k = 0; k < KC; ++k) {
            fv4 m4 = ((const fv4*)mus)[k * DV + tid];
            mu[k][0] = m4.x; mu[k][1] = m4.y; mu[k][2] = m4.z; mu[k][3] = m4.w;
        }

        fv4* ov = (fv4*)out;
        for (int rr = 0; rr < RPB; rr += 4) {
            fv4 v[4];
#pragma unroll
            for (int i = 0; i < 4; ++i)
                v[i] = xv[(row0 + rr + i) * DV + tid];
#pragma unroll
            for (int i = 0; i < 4; ++i) {
                float xin[4] = { v[i].x, v[i].y, v[i].z, v[i].w };
                float o[4];
#pragma unroll
                for (int e = 0; e < 4; ++e) {
                    float xe = xin[e];
                    float fam = 0.f;
#pragma unroll
                    for (int k = 0; k < KC; ++k)
                        fam += rk[k] * __builtin_amdgcn_exp2f(-tl[e] * fabsf(xe - mu[k][e]));
                    float y = xe * (1.f - al[e] * fam);
                    float z = 0.79788456f * (y + 0.044715f * y * y * y);
                    float e2 = __builtin_amdgcn_exp2f(2.88539008f * z);
                    float th = 1.f - 2.f * __builtin_amdgcn_rcpf(e2 + 1.f);
                    o[e] = 0.5f * y * (1.f + th);
                }
                fv4 res; res.x = o[0]; res.y = o[1]; res.z = o[2]; res.w = o[3];
                __builtin_nontemporal_store(res, &ov[(row0 + rr + i) * DV + tid]);
            }
        }
    }
}

extern "C" void kernel_launch(void* const* d_in, const int* in_sizes, int n_in,
                              void* d_out, int out_size, void* d_ws, size_t ws_size,
                              hipStream_t stream) {
    const float* x         = (const float*)d_in[0];
    const float* mus       = (const float*)d_in[1];
    const float* wmix      = (const float*)d_in[2];
    const float* log_tau   = (const float*)d_in[3];
    const float* log_blend = (const float*)d_in[4];
    float* out = (float*)d_out;

    float* part   = (float*)d_ws;               // NBLK*DD floats (2 MB)
    float* colsum = part + (long)NBLK * DD;     // DD floats (4 KB)

    void* args[] = { (void*)&x, (void*)&mus, (void*)&wmix, (void*)&log_tau,
                     (void*)&log_blend, (void*)&out, (void*)&part, (void*)&colsum };
    (void)hipLaunchCooperativeKernel((const void*)fused, dim3(NBLK), dim3(256),
                                     args, 0, stream);
}

// Round 7
// 83.342 us; speedup vs baseline: 2.4806x; 2.4806x over previous
//
#include <hip/hip_runtime.h>
#include <math.h>

// Problem constants (B=16, T=2048, D=1024, K=8)
#define BT    32768   // B*T rows
#define DD    1024    // D
#define DV    256     // float4 per row (D/4)
#define KC    8       // clusters
#define NPART 512     // kA grid = number of partial-sum rows
#define G3    2048    // kC grid
#define RPB3  16      // rows per kC block = BT/G3

// clang native vector type (required by __builtin_nontemporal_store).
typedef float fv4 __attribute__((ext_vector_type(4)));

// ---------------------------------------------------------------------------
// kA: partial column sums of x (BT x DD). Thread t owns fv4-column t.
// 8-deep explicit load batching (round-1 depth-1 version was latency-bound
// at 594 GB/s). Non-atomic stores -> no memset node, no contention.
// ---------------------------------------------------------------------------
__global__ __launch_bounds__(256) void kA_partial(const float* __restrict__ x,
                                                  float* __restrict__ part,
                                                  int rows_per_blk) {
    const int tid = threadIdx.x;
    const fv4* xv = (const fv4*)x;
    const long row0 = (long)blockIdx.x * rows_per_blk;
    fv4 acc = (fv4)(0.f);

    for (int r = 0; r < rows_per_blk; r += 8) {
        fv4 v[8];
#pragma unroll
        for (int i = 0; i < 8; ++i)
            v[i] = xv[(row0 + r + i) * DV + tid];
#pragma unroll
        for (int i = 0; i < 8; ++i) acc += v[i];
    }

    ((fv4*)part)[(long)blockIdx.x * DV + tid] = acc;
}

// ---------------------------------------------------------------------------
// kB: parallel fold. Block b reduces fv4-column b across the NPART partial
// rows: thread t sums rows t and t+256, then LDS tree -> colsum[b].
// 2 MB total, L2-resident; replaces round-4's serial single-block fold
// (the suspected ~30us hidden cost).
// ---------------------------------------------------------------------------
__global__ __launch_bounds__(256) void kB_fold(const float* __restrict__ part,
                                               float* __restrict__ colsum) {
    const int tid = threadIdx.x;
    const int b = blockIdx.x;          // fv4-column index, 0..DV-1
    __shared__ fv4 red[256];

    fv4 a = ((const fv4*)part)[(long)tid * DV + b] +
            ((const fv4*)part)[(long)(tid + 256) * DV + b];
    red[tid] = a;
    __syncthreads();
#pragma unroll
    for (int s = 128; s > 0; s >>= 1) {
        if (tid < s) red[tid] += red[tid + s];
        __syncthreads();
    }
    if (tid == 0) ((fv4*)colsum)[b] = red[0];
}

// ---------------------------------------------------------------------------
// kC: every block redundantly computes responsibilities r[0..7] from colsum
// (4KB) + mus (32KB) — both L2-broadcast, ~2us aggregate — then the
// famil/GELU elementwise pass over its 16 rows. 4-deep batched loads;
// non-temporal store keeps x resident in L3 for the (L3-served) re-read.
// ---------------------------------------------------------------------------
__global__ __launch_bounds__(256) void kC_main(const float* __restrict__ x,
                                               const float* __restrict__ mus,
                                               const float* __restrict__ wmix,
                                               const float* __restrict__ log_tau,
                                               const float* __restrict__ log_blend,
                                               const float* __restrict__ colsum,
                                               float* __restrict__ out,
                                               int rows_per_blk) {
    const int tid = threadIdx.x;
    const long row0 = (long)blockIdx.x * rows_per_blk;
    const fv4* xv = (const fv4*)x;

    // ---- responsibilities (redundant per block) --------------------------
    float rk[KC];
    {
        const float inv_bt = 1.0f / (float)BT;
        fv4 s = ((const fv4*)colsum)[tid];
        float m[4] = { s.x * inv_bt, s.y * inv_bt, s.z * inv_bt, s.w * inv_bt };
        float prt[KC];
#pragma unroll
        for (int k = 0; k < KC; ++k) {
            fv4 mu = ((const fv4*)mus)[k * DV + tid];
            float d0 = m[0] - mu.x, d1 = m[1] - mu.y;
            float d2 = m[2] - mu.z, d3 = m[3] - mu.w;
            prt[k] = d0 * d0 + d1 * d1 + d2 * d2 + d3 * d3;
        }
        __shared__ float l2[KC][4];
        const int lane = tid & 63, wv = tid >> 6;
#pragma unroll
        for (int k = 0; k < KC; ++k) {
            float v = prt[k];
#pragma unroll
            for (int off = 32; off > 0; off >>= 1) v += __shfl_down(v, off, 64);
            if (lane == 0) l2[k][wv] = v;
        }
        __syncthreads();
        float logits[KC], mx = -1e30f;
#pragma unroll
        for (int k = 0; k < KC; ++k) {
            float tot = l2[k][0] + l2[k][1] + l2[k][2] + l2[k][3];
            float dist = sqrtf(tot * (1.0f / (float)DD));
            logits[k] = logf(wmix[k]) - dist;
            mx = fmaxf(mx, logits[k]);
        }
        float se = 0.f, e[KC];
#pragma unroll
        for (int k = 0; k < KC; ++k) { e[k] = expf(logits[k] - mx); se += e[k]; }
        float is = 1.f / se;
#pragma unroll
        for (int k = 0; k < KC; ++k) rk[k] = e[k] * is;
    }

    // ---- famil / GELU main pass ------------------------------------------
    const float LOG2E = 1.44269504f;
    fv4 lt = ((const fv4*)log_tau)[tid];
    fv4 lb = ((const fv4*)log_blend)[tid];
    float tl[4], al[4];
    tl[0] = __builtin_amdgcn_exp2f(lt.x * LOG2E) * LOG2E;
    tl[1] = __builtin_amdgcn_exp2f(lt.y * LOG2E) * LOG2E;
    tl[2] = __builtin_amdgcn_exp2f(lt.z * LOG2E) * LOG2E;
    tl[3] = __builtin_amdgcn_exp2f(lt.w * LOG2E) * LOG2E;
    al[0] = 1.f / (1.f + __builtin_amdgcn_exp2f(-lb.x * LOG2E));
    al[1] = 1.f / (1.f + __builtin_amdgcn_exp2f(-lb.y * LOG2E));
    al[2] = 1.f / (1.f + __builtin_amdgcn_exp2f(-lb.z * LOG2E));
    al[3] = 1.f / (1.f + __builtin_amdgcn_exp2f(-lb.w * LOG2E));

    float mu[KC][4];
#pragma unroll
    for (int k = 0; k < KC; ++k) {
        fv4 m4 = ((const fv4*)mus)[k * DV + tid];
        mu[k][0] = m4.x; mu[k][1] = m4.y; mu[k][2] = m4.z; mu[k][3] = m4.w;
    }

    fv4* ov = (fv4*)out;
    for (int rr = 0; rr < rows_per_blk; rr += 4) {
        fv4 v[4];
#pragma unroll
        for (int i = 0; i < 4; ++i)
            v[i] = xv[(row0 + rr + i) * DV + tid];
#pragma unroll
        for (int i = 0; i < 4; ++i) {
            float xin[4] = { v[i].x, v[i].y, v[i].z, v[i].w };
            float o[4];
#pragma unroll
            for (int e = 0; e < 4; ++e) {
                float xe = xin[e];
                float fam = 0.f;
#pragma unroll
                for (int k = 0; k < KC; ++k)
                    fam += rk[k] * __builtin_amdgcn_exp2f(-tl[e] * fabsf(xe - mu[k][e]));
                float y = xe * (1.f - al[e] * fam);
                float z = 0.79788456f * (y + 0.044715f * y * y * y);
                float e2 = __builtin_amdgcn_exp2f(2.88539008f * z);
                float th = 1.f - 2.f * __builtin_amdgcn_rcpf(e2 + 1.f);
                o[e] = 0.5f * y * (1.f + th);
            }
            fv4 res; res.x = o[0]; res.y = o[1]; res.z = o[2]; res.w = o[3];
            __builtin_nontemporal_store(res, &ov[(row0 + rr + i) * DV + tid]);
        }
    }
}

extern "C" void kernel_launch(void* const* d_in, const int* in_sizes, int n_in,
                              void* d_out, int out_size, void* d_ws, size_t ws_size,
                              hipStream_t stream) {
    const float* x         = (const float*)d_in[0];
    const float* mus       = (const float*)d_in[1];
    const float* wmix      = (const float*)d_in[2];
    const float* log_tau   = (const float*)d_in[3];
    const float* log_blend = (const float*)d_in[4];
    float* out = (float*)d_out;

    float* part   = (float*)d_ws;             // NPART*DD floats (2 MB)
    float* colsum = part + (long)NPART * DD;  // DD floats (4 KB)

    kA_partial<<<NPART, 256, 0, stream>>>(x, part, BT / NPART);
    kB_fold<<<DV, 256, 0, stream>>>(part, colsum);
    kC_main<<<G3, 256, 0, stream>>>(x, mus, wmix, log_tau, log_blend,
                                    colsum, out, RPB3);
}